// Round 8
// baseline (1811.486 us; speedup 1.0000x reference)
//
#include <hip/hip_runtime.h>
#include <hip/hip_bf16.h>

typedef __attribute__((ext_vector_type(8)))  short short8;
typedef __attribute__((ext_vector_type(16))) float floatx16;
typedef unsigned short ushort;

constexpr int SL  = 384;
constexpr int N2  = SL * SL;      // 147456
constexpr int CH  = 64;
constexpr int D1  = 788;
constexpr int D2  = 210;
constexpr float EPSF = 1e-5f;

constexpr int TX = 32, TY = 8;
constexpr int NBLK = (SL / TX) * (SL / TY);   // 576
constexpr int PBLK = N2 / 1024;               // 144 (pair2 blocks per oc-half)

__device__ __forceinline__ float lrelu(float v){ return v >= 0.f ? v : 0.01f * v; }
__device__ __forceinline__ ushort f2b(float f){
  __hip_bfloat16 h = __float2bfloat16(f); return *(ushort*)&h;
}
__device__ __forceinline__ float b2f(ushort u){
  __hip_bfloat16 h = *(__hip_bfloat16*)&u; return __bfloat162float(h);
}

__device__ __forceinline__ float wred(float v){
  #pragma unroll
  for (int o = 32; o; o >>= 1) v += __shfl_down(v, o, 64);
  return v;
}

// ---------------- per-channel stats over fp32 NCHW ----------------
__global__ void stats_k(const float* __restrict__ x, int n, float* __restrict__ part){
  const int c = blockIdx.y, s = blockIdx.x, S = gridDim.x;
  const int chunk = (n + S - 1) / S;
  const int st = s * chunk, en = min(n, st + chunk);
  const float* p = x + (size_t)c * n;
  float sm = 0.f, ss = 0.f;
  for (int i = st + threadIdx.x; i < en; i += blockDim.x){
    float v = p[i]; sm += v; ss += v * v;
  }
  sm = wred(sm); ss = wred(ss);
  __shared__ float aux[8];
  const int wid = threadIdx.x >> 6, lane = threadIdx.x & 63;
  if (lane == 0){ aux[wid] = sm; aux[4 + wid] = ss; }
  __syncthreads();
  if (threadIdx.x == 0){
    part[((size_t)c * S + s) * 2]     = aux[0] + aux[1] + aux[2] + aux[3];
    part[((size_t)c * S + s) * 2 + 1] = aux[4] + aux[5] + aux[6] + aux[7];
  }
}

__global__ void stats_final_k(const float* __restrict__ part, int C, int S, float ninv,
                              float* __restrict__ mean, float* __restrict__ rstd){
  const int c = blockIdx.x * blockDim.x + threadIdx.x;
  if (c >= C) return;
  float sm = 0.f, ss = 0.f;
  for (int s = 0; s < S; ++s){ sm += part[((size_t)c * S + s) * 2]; ss += part[((size_t)c * S + s) * 2 + 1]; }
  const float m = sm * ninv;
  mean[c] = m;
  rstd[c] = rsqrtf(ss * ninv - m * m + EPSF);
}

__global__ void statsaffine_k(const float* __restrict__ part, int S, float ninv,
                              const float* __restrict__ g, const float* __restrict__ be,
                              int goff, float* __restrict__ ao, float* __restrict__ bo){
  const int c = threadIdx.x;
  if (c >= CH) return;
  float sm = 0.f, ss = 0.f;
  for (int s = 0; s < S; ++s){ sm += part[((size_t)c * S + s) * 2]; ss += part[((size_t)c * S + s) * 2 + 1]; }
  const float m = sm * ninv;
  const float r = rsqrtf(ss * ninv - m * m + EPSF);
  const float a = r * g[goff + c];
  ao[c] = a;
  bo[c] = be[goff + c] - m * a;
}

// ---------------- 1d branch (D1 split x4 for occupancy) ----------------
__global__ void rowcol_k(const float* __restrict__ x1d, const float* __restrict__ W1,
                         const float* __restrict__ r1, float* __restrict__ rcP){
  const int idx = blockIdx.x * 256 + threadIdx.x;   // (half, c, l)
  const int chunk = blockIdx.y;
  const int half = idx / (CH * SL);
  const int rem  = idx % (CH * SL);
  const int c = rem / SL, l = rem % SL;
  const int d0 = chunk * 197, d1 = min(D1, d0 + 197);
  const float* wp = W1 + (size_t)c * (2 * D1) + (size_t)half * D1;
  float acc = 0.f;
  for (int d = d0; d < d1; ++d)
    acc += wp[d] * (x1d[(size_t)d * SL + l] * r1[d]);
  rcP[(size_t)chunk * (2 * CH * SL) + idx] = acc;
}

__global__ void rowcol_stats_k(const float* __restrict__ rcP,
                               float* __restrict__ m1, float* __restrict__ rs1){
  const int c = blockIdx.x;
  float sr = 0, ssr = 0, sc = 0, ssc = 0;
  for (int i = threadIdx.x; i < SL; i += blockDim.x){
    float r = 0, q = 0;
    #pragma unroll
    for (int k = 0; k < 4; ++k){
      r += rcP[(size_t)k * (2*CH*SL) + c * SL + i];
      q += rcP[(size_t)k * (2*CH*SL) + CH*SL + c * SL + i];
    }
    sr += r; ssr += r * r; sc += q; ssc += q * q;
  }
  sr = wred(sr); ssr = wred(ssr); sc = wred(sc); ssc = wred(ssc);
  __shared__ float aux[16];
  const int wid = threadIdx.x >> 6, lane = threadIdx.x & 63;
  if (lane == 0){ aux[wid] = sr; aux[4+wid] = ssr; aux[8+wid] = sc; aux[12+wid] = ssc; }
  __syncthreads();
  if (threadIdx.x == 0){
    float a = 0, b = 0, d = 0, e = 0;
    for (int i = 0; i < 4; ++i){ a += aux[i]; b += aux[4+i]; d += aux[8+i]; e += aux[12+i]; }
    const float mr = a / SL, mc = d / SL;
    const float vr = b / SL - mr * mr, vc = e / SL - mc * mc;
    m1[c]  = mr + mc;
    rs1[c] = rsqrtf(vr + vc + EPSF);
  }
}

__global__ void rowcolT_k(const float* __restrict__ rcP,
                          const float* __restrict__ m1, const float* __restrict__ rs1,
                          const float* __restrict__ g1, const float* __restrict__ b1,
                          float* __restrict__ rowT, float* __restrict__ colT){
  const int i = blockIdx.x * 256 + threadIdx.x;   // 384*64
  const int l = i >> 6, c = i & 63;
  float r = 0, q = 0;
  #pragma unroll
  for (int k = 0; k < 4; ++k){
    r += rcP[(size_t)k * (2*CH*SL) + c * SL + l];
    q += rcP[(size_t)k * (2*CH*SL) + CH*SL + c * SL + l];
  }
  const float a  = rs1[c] * g1[c];
  const float bb = b1[c] - m1[c] * a;
  rowT[i] = r * a + bb;
  colT[i] = q * a;
}

__global__ __launch_bounds__(256) void pair1n_k(const float* __restrict__ rowT,
                                                const float* __restrict__ colT,
                                                ushort* __restrict__ out){
  const size_t q = ((size_t)blockIdx.x * 256 + threadIdx.x) * 16;
  const int px = (int)(q >> 6), c0 = (int)(q & 63);
  const int i = px / SL, j = px % SL;
  const float4* rp = (const float4*)&rowT[i * 64 + c0];
  const float4* cp = (const float4*)&colT[j * 64 + c0];
  ushort o[16];
  #pragma unroll
  for (int k = 0; k < 4; ++k){
    float4 r = rp[k], cl = cp[k];
    o[4*k]   = f2b(lrelu(r.x + cl.x));
    o[4*k+1] = f2b(lrelu(r.y + cl.y));
    o[4*k+2] = f2b(lrelu(r.z + cl.z));
    o[4*k+3] = f2b(lrelu(r.w + cl.w));
  }
  *(short8*)&out[q]     = *(short8*)&o[0];
  *(short8*)&out[q + 8] = *(short8*)&o[8];
}

// ---------------- 2d branch: oc-split VALU GEMM, 4 px/thread + fused stats ----------------
__global__ void w2eff_k(const float* __restrict__ W2, const float* __restrict__ r2,
                        float* __restrict__ w2e){
  const int c = threadIdx.x;
  if (c >= CH) return;
  for (int d = 0; d < D2; ++d)
    w2e[d * CH + c] = W2[(size_t)c * D2 + d] * r2[d];
}

__global__ __launch_bounds__(256) void pair2v_k(const float* __restrict__ x2,
                                                const float* __restrict__ w2e,
                                                ushort* __restrict__ out,
                                                float* __restrict__ part){
  const int t = blockIdx.x * 256 + threadIdx.x;   // 4-px group index
  const int oh = blockIdx.y;                      // oc half
  float4 acc[32];
  #pragma unroll
  for (int c = 0; c < 32; ++c) acc[c] = make_float4(0.f, 0.f, 0.f, 0.f);
  const float4* x4 = (const float4*)x2;
  for (int d = 0; d < D2; ++d){
    const float4 xv = x4[(size_t)d * (N2 / 4) + t];
    const float4* w4 = (const float4*)(w2e + d * CH + oh * 32);
    #pragma unroll
    for (int q = 0; q < 8; ++q){
      float4 w = w4[q];
      #pragma unroll
      for (int j = 0; j < 4; ++j){
        const float wj = (j == 0) ? w.x : (j == 1) ? w.y : (j == 2) ? w.z : w.w;
        acc[4*q+j].x += wj * xv.x; acc[4*q+j].y += wj * xv.y;
        acc[4*q+j].z += wj * xv.z; acc[4*q+j].w += wj * xv.w;
      }
    }
  }
  const int p4 = t * 4;
  #pragma unroll
  for (int j = 0; j < 4; ++j){
    ushort o[32];
    #pragma unroll
    for (int c = 0; c < 32; ++c){
      const float v = (j == 0) ? acc[c].x : (j == 1) ? acc[c].y : (j == 2) ? acc[c].z : acc[c].w;
      o[c] = f2b(v);
    }
    ushort* op = &out[(size_t)(p4 + j) * 64 + oh * 32];
    *(short8*)&op[0]  = *(short8*)&o[0];
    *(short8*)&op[8]  = *(short8*)&o[8];
    *(short8*)&op[16] = *(short8*)&o[16];
    *(short8*)&op[24] = *(short8*)&o[24];
  }
  __shared__ float sc[4 * 32 * 2];
  const int wid = threadIdx.x >> 6, lane = threadIdx.x & 63;
  #pragma unroll
  for (int c = 0; c < 32; ++c){
    float v  = acc[c].x + acc[c].y + acc[c].z + acc[c].w;
    float v2 = acc[c].x*acc[c].x + acc[c].y*acc[c].y + acc[c].z*acc[c].z + acc[c].w*acc[c].w;
    #pragma unroll
    for (int o = 1; o < 64; o <<= 1){ v += __shfl_xor(v, o, 64); v2 += __shfl_xor(v2, o, 64); }
    if (lane == 0){ sc[(wid*32+c)*2] = v; sc[(wid*32+c)*2+1] = v2; }
  }
  __syncthreads();
  if (threadIdx.x < 32){
    float sm = 0.f, ss = 0.f;
    #pragma unroll
    for (int w = 0; w < 4; ++w){ sm += sc[(w*32+threadIdx.x)*2]; ss += sc[(w*32+threadIdx.x)*2+1]; }
    const int oc = oh * 32 + threadIdx.x;
    part[((size_t)oc * PBLK + blockIdx.x) * 2]     = sm;
    part[((size_t)oc * PBLK + blockIdx.x) * 2 + 1] = ss;
  }
}

// NHWC affine+leaky in place
__global__ __launch_bounds__(256) void norm_nhwc_k(ushort* __restrict__ x,
                                                   const float* __restrict__ a,
                                                   const float* __restrict__ b){
  const size_t q = ((size_t)blockIdx.x * 256 + threadIdx.x) * 16;
  const int c0 = (int)(q & 63);
  short8 v0 = *(short8*)&x[q], v1 = *(short8*)&x[q + 8];
  ushort o[16];
  #pragma unroll
  for (int k = 0; k < 8; ++k){
    o[k]   = f2b(lrelu(b2f((ushort)v0[k]) * a[c0+k]   + b[c0+k]));
    o[k+8] = f2b(lrelu(b2f((ushort)v1[k]) * a[c0+8+k] + b[c0+8+k]));
  }
  *(short8*)&x[q]     = *(short8*)&o[0];
  *(short8*)&x[q + 8] = *(short8*)&o[8];
}

// W3 [c][2CH] fp32 -> bf16 A-operand layout [kc(8)][half(2)][oc(64)][j(8)]
__global__ void w3b_k(const float* __restrict__ W3, ushort* __restrict__ w3b){
  const int i = blockIdx.x * 256 + threadIdx.x;   // 8192
  const int j    = i & 7;
  const int oc   = (i >> 3) & 63;
  const int half = (i >> 9) & 1;
  const int kc   = i >> 10;
  const int e    = kc * 16 + half * 8 + j;
  w3b[i] = f2b(W3[oc * (2 * CH) + e]);
}

// ---------------- MFMA mix: K=128 (A || Bb), direct-global B, in-place out ----------------
__global__ __launch_bounds__(256) void mixm_k(const ushort* __restrict__ A,
                                              const ushort* __restrict__ Bv,
                                              const ushort* __restrict__ w3b,
                                              ushort* __restrict__ out,
                                              float* __restrict__ part){
  __shared__ __align__(16) unsigned char ldsraw[256 * 136 + 4 * CH * 2 * 4];
  const int tid = threadIdx.x, lane = tid & 63, wid = tid >> 6;
  const int ln = lane & 31, half = lane >> 5;
  const int px0 = blockIdx.x * 256;
  floatx16 acc[2][2];
  #pragma unroll
  for (int mt = 0; mt < 2; ++mt)
    #pragma unroll
    for (int nt = 0; nt < 2; ++nt)
      #pragma unroll
      for (int r = 0; r < 16; ++r) acc[mt][nt][r] = 0.f;

  const size_t rb0 = ((size_t)(px0 + wid * 64 + ln)) * 64;
  const size_t rb1 = rb0 + (size_t)32 * 64;
  #pragma unroll
  for (int kc = 0; kc < 8; ++kc){
    const ushort* src = (kc < 4) ? A : Bv;
    const int co = (kc & 3) * 16 + half * 8;
    const ushort* ab = w3b + ((size_t)(kc * 2 + half)) * 512;
    short8 a0 = *(const short8*)&ab[ln * 8];
    short8 a1 = *(const short8*)&ab[256 + ln * 8];
    short8 b0 = *(const short8*)&src[rb0 + co];
    short8 b1 = *(const short8*)&src[rb1 + co];
    acc[0][0] = __builtin_amdgcn_mfma_f32_32x32x16_bf16(a0, b0, acc[0][0], 0, 0, 0);
    acc[1][0] = __builtin_amdgcn_mfma_f32_32x32x16_bf16(a1, b0, acc[1][0], 0, 0, 0);
    acc[0][1] = __builtin_amdgcn_mfma_f32_32x32x16_bf16(a0, b1, acc[0][1], 0, 0, 0);
    acc[1][1] = __builtin_amdgcn_mfma_f32_32x32x16_bf16(a1, b1, acc[1][1], 0, 0, 0);
  }

  ushort* tb = (ushort*)ldsraw;
  float*  sc = (float*)(ldsraw + 256 * 136);
  #pragma unroll
  for (int mt = 0; mt < 2; ++mt)
    #pragma unroll
    for (int nt = 0; nt < 2; ++nt){
      const int pxl = (2*wid + nt) * 32 + ln;
      #pragma unroll
      for (int rq = 0; rq < 4; ++rq){
        const int oc0 = mt*32 + 8*rq + 4*half;
        #pragma unroll
        for (int k = 0; k < 2; ++k){
          const int r = rq*4 + k*2;
          unsigned pk = (unsigned)f2b(acc[mt][nt][r]) | ((unsigned)f2b(acc[mt][nt][r+1]) << 16);
          *(unsigned*)&tb[pxl * 68 + oc0 + k*2] = pk;
        }
      }
    }
  #pragma unroll
  for (int mt = 0; mt < 2; ++mt)
    #pragma unroll
    for (int rq = 0; rq < 4; ++rq)
      #pragma unroll
      for (int t = 0; t < 4; ++t){
        const int r = rq*4 + t;
        float v  = acc[mt][0][r] + acc[mt][1][r];
        float v2 = acc[mt][0][r]*acc[mt][0][r] + acc[mt][1][r]*acc[mt][1][r];
        #pragma unroll
        for (int o = 1; o < 32; o <<= 1){ v += __shfl_xor(v, o, 64); v2 += __shfl_xor(v2, o, 64); }
        if (ln == 0){
          const int oc = mt*32 + 8*rq + 4*half + t;
          sc[(wid*CH + oc)*2] = v; sc[(wid*CH + oc)*2 + 1] = v2;
        }
      }
  __syncthreads();
  {
    const int px = lane >> 1, pt = lane & 1;
    #pragma unroll
    for (int nt = 0; nt < 2; ++nt){
      const int rr = 2*wid + nt;
      const ushort* sp = &tb[(rr*32 + px) * 68 + pt*32];
      ushort* dp = &out[((size_t)(px0 + rr*32 + px)) * 64 + pt*32];
      #pragma unroll
      for (int k = 0; k < 8; ++k){
        uint2 v = *(const uint2*)&sp[k*4];
        *(uint2*)&dp[k*4] = v;
      }
    }
  }
  if (tid < CH){
    float sm = 0.f, ss = 0.f;
    #pragma unroll
    for (int w = 0; w < 4; ++w){ sm += sc[(w*CH + tid)*2]; ss += sc[(w*CH + tid)*2 + 1]; }
    part[((size_t)tid * NBLK + blockIdx.x) * 2]     = sm;
    part[((size_t)tid * NBLK + blockIdx.x) * 2 + 1] = ss;
  }
}

// ---------------- norm + residual; X fp32 NCHW (d_out), Xb bf16 NHWC ----------------
__global__ __launch_bounds__(256) void norm_res_k(const ushort* __restrict__ src,
                                                  const float* __restrict__ a,
                                                  const float* __restrict__ b,
                                                  float* __restrict__ X,
                                                  ushort* __restrict__ Xb,
                                                  int doRes){
  __shared__ float tf[64 * 68];
  const int tid = threadIdx.x;
  const int p0 = blockIdx.x * 64;
  const int pxl = tid >> 2, c0 = (tid & 3) * 16;
  {
    const ushort* sp = &src[(size_t)(p0 + pxl) * 64 + c0];
    short8 v0 = *(const short8*)&sp[0], v1 = *(const short8*)&sp[8];
    #pragma unroll
    for (int k = 0; k < 8; ++k){
      tf[(c0+k)*68 + pxl]   = lrelu(b2f((ushort)v0[k]) * a[c0+k]   + b[c0+k]);
      tf[(c0+8+k)*68 + pxl] = lrelu(b2f((ushort)v1[k]) * a[c0+8+k] + b[c0+8+k]);
    }
  }
  __syncthreads();
  {
    const int c = tid >> 2, part = tid & 3;
    const size_t gb = (size_t)c * N2 + p0 + part * 16;
    float w[16];
    #pragma unroll
    for (int k = 0; k < 16; ++k) w[k] = tf[c*68 + part*16 + k];
    if (doRes){
      #pragma unroll
      for (int k = 0; k < 16; ++k) w[k] += X[gb + k];
      #pragma unroll
      for (int k = 0; k < 16; ++k) tf[c*68 + part*16 + k] = w[k];
    }
    #pragma unroll
    for (int k = 0; k < 16; ++k) X[gb + k] = w[k];
  }
  if (Xb){
    __syncthreads();
    ushort o[16];
    #pragma unroll
    for (int k = 0; k < 16; ++k) o[k] = f2b(tf[(c0+k)*68 + pxl]);
    ushort* xp = &Xb[(size_t)(p0 + pxl) * 64 + c0];
    *(short8*)&xp[0] = *(short8*)&o[0];
    *(short8*)&xp[8] = *(short8*)&o[8];
  }
}

// conv weights [conv][oc][ic][3][3] fp32 -> bf16 [conv][tap][kc][half][oc][8j]
__global__ void wt_k(const float* __restrict__ w, ushort* __restrict__ wt){
  const int i = blockIdx.x * 256 + threadIdx.x;   // 368640
  const int j    = i & 7;
  const int oc   = (i >> 3) & 63;
  const int half = (i >> 9) & 1;
  const int kc   = (i >> 10) & 3;
  const int tap  = (i / 4096) % 9;
  const int cv   = i / 36864;
  const int ic   = kc * 16 + half * 8 + j;
  wt[i] = f2b(w[((size_t)(cv * CH + oc) * CH + ic) * 9 + tap]);
}

// ---------------- MFMA conv: weights in LDS, interior fast path, fused stats ----------------
template<int DIL>
__global__ __launch_bounds__(256, 2) void convd_k(const ushort* __restrict__ in,
                                                  const ushort* __restrict__ wg,
                                                  ushort* __restrict__ out,
                                                  float* __restrict__ part){
  __shared__ __align__(16) ushort wl[36864];     // 72 KB: weights, reused by epilogue
  const int tid = threadIdx.x, lane = tid & 63, wid = tid >> 6;
  const int ln = lane & 31, half = lane >> 5;
  const int bx = blockIdx.x % (SL / TX), by = blockIdx.x / (SL / TX);
  const int xg = bx * TX + ln;

  #pragma unroll
  for (int i = 0; i < 18; ++i){
    const int idx = (i * 256 + tid) * 8;
    *(short8*)&wl[idx] = *(const short8*)&wg[idx];
  }
  __syncthreads();

  floatx16 acc[2][2];
  #pragma unroll
  for (int mt = 0; mt < 2; ++mt)
    #pragma unroll
    for (int nt = 0; nt < 2; ++nt)
      #pragma unroll
      for (int r = 0; r < 16; ++r) acc[mt][nt][r] = 0.f;

  const int row0 = by * TY + 2 * wid;
  const ushort* bp0 = in + ((size_t)row0 * SL + xg) * 64;
  const bool interior = (bx >= 1) && (bx <= (SL/TX) - 2) && (by >= 1) && (by <= (SL/TY) - 2);

  if (interior){
    #pragma unroll
    for (int tap = 0; tap < 9; ++tap){
      const int dy = (tap / 3 - 1) * DIL, dx = (tap % 3 - 1) * DIL;
      const ushort* r0 = bp0 + (dy * SL + dx) * 64;
      const ushort* r1 = r0 + SL * 64;
      #pragma unroll
      for (int kc = 0; kc < 4; ++kc){
        const int wo = ((tap * 4 + kc) * 2 + half) * 512;
        short8 a0 = *(const short8*)&wl[wo + ln * 8];
        short8 a1 = *(const short8*)&wl[wo + 256 + ln * 8];
        const int co = kc * 16 + half * 8;
        short8 b0 = *(const short8*)&r0[co];
        short8 b1 = *(const short8*)&r1[co];
        acc[0][0] = __builtin_amdgcn_mfma_f32_32x32x16_bf16(a0, b0, acc[0][0], 0, 0, 0);
        acc[1][0] = __builtin_amdgcn_mfma_f32_32x32x16_bf16(a1, b0, acc[1][0], 0, 0, 0);
        acc[0][1] = __builtin_amdgcn_mfma_f32_32x32x16_bf16(a0, b1, acc[0][1], 0, 0, 0);
        acc[1][1] = __builtin_amdgcn_mfma_f32_32x32x16_bf16(a1, b1, acc[1][1], 0, 0, 0);
      }
    }
  } else {
    #pragma unroll
    for (int tap = 0; tap < 9; ++tap){
      const int dy = (tap / 3 - 1) * DIL, dx = (tap % 3 - 1) * DIL;
      const int gx = xg + dx;
      const bool okx = (unsigned)gx < (unsigned)SL;
      const int gy0 = row0 + dy, gy1 = gy0 + 1;
      const bool ok0 = okx && ((unsigned)gy0 < (unsigned)SL);
      const bool ok1 = okx && ((unsigned)gy1 < (unsigned)SL);
      const size_t r0 = ((size_t)(gy0 * SL + gx)) * 64;
      const size_t r1 = ((size_t)(gy1 * SL + gx)) * 64;
      #pragma unroll
      for (int kc = 0; kc < 4; ++kc){
        const int wo = ((tap * 4 + kc) * 2 + half) * 512;
        short8 a0 = *(const short8*)&wl[wo + ln * 8];
        short8 a1 = *(const short8*)&wl[wo + 256 + ln * 8];
        const int co = kc * 16 + half * 8;
        short8 b0 = {0,0,0,0,0,0,0,0}, b1 = {0,0,0,0,0,0,0,0};
        if (ok0) b0 = *(const short8*)&in[r0 + co];
        if (ok1) b1 = *(const short8*)&in[r1 + co];
        acc[0][0] = __builtin_amdgcn_mfma_f32_32x32x16_bf16(a0, b0, acc[0][0], 0, 0, 0);
        acc[1][0] = __builtin_amdgcn_mfma_f32_32x32x16_bf16(a1, b0, acc[1][0], 0, 0, 0);
        acc[0][1] = __builtin_amdgcn_mfma_f32_32x32x16_bf16(a0, b1, acc[0][1], 0, 0, 0);
        acc[1][1] = __builtin_amdgcn_mfma_f32_32x32x16_bf16(a1, b1, acc[1][1], 0, 0, 0);
      }
    }
  }

  // epilogue: reuse weight LDS for transpose -> coalesced NHWC stores + fused stats
  __syncthreads();
  ushort* tb = wl;                                  // [256 px][68 ushorts]
  float*  sc = (float*)&wl[256 * 68];               // [4][64][2]
  #pragma unroll
  for (int mt = 0; mt < 2; ++mt)
    #pragma unroll
    for (int nt = 0; nt < 2; ++nt){
      const int pxl = (2*wid + nt) * 32 + ln;
      #pragma unroll
      for (int rq = 0; rq < 4; ++rq){
        const int oc0 = mt*32 + 8*rq + 4*half;
        #pragma unroll
        for (int k = 0; k < 2; ++k){
          const int r = rq*4 + k*2;
          unsigned pk = (unsigned)f2b(acc[mt][nt][r]) | ((unsigned)f2b(acc[mt][nt][r+1]) << 16);
          *(unsigned*)&tb[pxl * 68 + oc0 + k*2] = pk;
        }
      }
    }
  #pragma unroll
  for (int mt = 0; mt < 2; ++mt)
    #pragma unroll
    for (int rq = 0; rq < 4; ++rq)
      #pragma unroll
      for (int t = 0; t < 4; ++t){
        const int r = rq*4 + t;
        float v  = acc[mt][0][r] + acc[mt][1][r];
        float v2 = acc[mt][0][r]*acc[mt][0][r] + acc[mt][1][r]*acc[mt][1][r];
        #pragma unroll
        for (int o = 1; o < 32; o <<= 1){ v += __shfl_xor(v, o, 64); v2 += __shfl_xor(v2, o, 64); }
        if (ln == 0){
          const int oc = mt*32 + 8*rq + 4*half + t;
          sc[(wid*CH + oc)*2] = v; sc[(wid*CH + oc)*2 + 1] = v2;
        }
      }
  __syncthreads();
  {
    const int px = lane >> 1, pt = lane & 1;
    #pragma unroll
    for (int nt = 0; nt < 2; ++nt){
      const int rr = 2*wid + nt;
      const int gy = by*TY + rr;
      const ushort* sp = &tb[(rr*32 + px) * 68 + pt*32];
      ushort* dp = &out[((size_t)(gy * SL) + bx*TX + px) * 64 + pt*32];
      #pragma unroll
      for (int k = 0; k < 8; ++k){
        uint2 v = *(const uint2*)&sp[k*4];
        *(uint2*)&dp[k*4] = v;
      }
    }
  }
  if (tid < CH){
    float sm = 0.f, ss = 0.f;
    #pragma unroll
    for (int w = 0; w < 4; ++w){ sm += sc[(w*CH + tid)*2]; ss += sc[(w*CH + tid)*2 + 1]; }
    part[((size_t)tid * NBLK + blockIdx.x) * 2]     = sm;
    part[((size_t)tid * NBLK + blockIdx.x) * 2 + 1] = ss;
  }
}

static void launch_conv(int dil, const ushort* src, const ushort* wgl,
                        ushort* dst, float* part, hipStream_t s){
  switch (dil){
    case 1:  convd_k<1><<<NBLK, 256, 0, s>>>(src, wgl, dst, part); break;
    case 2:  convd_k<2><<<NBLK, 256, 0, s>>>(src, wgl, dst, part); break;
    default: convd_k<4><<<NBLK, 256, 0, s>>>(src, wgl, dst, part); break;
  }
}

extern "C" void kernel_launch(void* const* d_in, const int* in_sizes, int n_in,
                              void* d_out, int out_size, void* d_ws, size_t ws_size,
                              hipStream_t stream){
  const float* x1d    = (const float*)d_in[0];
  const float* x2     = (const float*)d_in[1];
  const float* W1     = (const float*)d_in[2];
  const float* g1     = (const float*)d_in[3];
  const float* b1     = (const float*)d_in[4];
  const float* W2     = (const float*)d_in[5];
  const float* res_w  = (const float*)d_in[11];
  const float* res_g  = (const float*)d_in[13];
  const float* res_be = (const float*)d_in[14];
  float* X = (float*)d_out;                        // fp32 NCHW residual stream

  unsigned char* wp = (unsigned char*)d_ws;
  ushort* A   = (ushort*)wp; wp += (size_t)N2 * 64 * 2;
  ushort* Bb  = (ushort*)wp; wp += (size_t)N2 * 64 * 2;
  ushort* Xb  = (ushort*)wp; wp += (size_t)N2 * 64 * 2;
  ushort* wt  = (ushort*)wp; wp += (size_t)368640 * 2;
  ushort* w3b = (ushort*)wp; wp += (size_t)8192 * 2;
  float* fw = (float*)wp;
  float* rcP  = fw; fw += 4 * 2 * CH * SL;
  float* rowT = fw; fw += SL * CH;
  float* colT = fw; fw += SL * CH;
  float* s1m  = fw; fw += D1;   float* s1r = fw; fw += D1;
  float* s2m  = fw; fw += 256;  float* s2r = fw; fw += 256;
  float* m1   = fw; fw += 64;   float* rs1 = fw; fw += 64;
  float* aA   = fw; fw += 64;   float* bA  = fw; fw += 64;
  float* aB   = fw; fw += 64;   float* bB  = fw; fw += 64;
  float* w2e  = fw; fw += D2 * CH;
  float* part = fw; fw += CH * NBLK * 2;

  // ---- 1d branch
  stats_k<<<dim3(1, D1), 256, 0, stream>>>(x1d, SL, part);
  stats_final_k<<<(D1 + 255) / 256, 256, 0, stream>>>(part, D1, 1, 1.f / SL, s1m, s1r);
  rowcol_k<<<dim3(2 * CH * SL / 256, 4), 256, 0, stream>>>(x1d, W1, s1r, rcP);
  rowcol_stats_k<<<CH, 256, 0, stream>>>(rcP, m1, rs1);
  rowcolT_k<<<SL * CH / 256, 256, 0, stream>>>(rcP, m1, rs1, g1, b1, rowT, colT);
  pair1n_k<<<N2 * 64 / 4096, 256, 0, stream>>>(rowT, colT, A);

  // ---- 2d branch
  stats_k<<<dim3(16, D2), 256, 0, stream>>>(x2, N2, part);
  stats_final_k<<<1, 256, 0, stream>>>(part, D2, 16, 1.f / N2, s2m, s2r);
  w2eff_k<<<1, 64, 0, stream>>>(W2, s2r, w2e);
  pair2v_k<<<dim3(PBLK, 2), 256, 0, stream>>>(x2, w2e, Bb, part);
  statsaffine_k<<<1, 64, 0, stream>>>(part, PBLK, 1.f / N2,
      (const float*)d_in[6], (const float*)d_in[7], 0, aA, bA);
  norm_nhwc_k<<<N2 * 64 / 4096, 256, 0, stream>>>(Bb, aA, bA);

  // ---- mix (MFMA, in-place over A) + bootstrap X
  w3b_k<<<32, 256, 0, stream>>>((const float*)d_in[8], w3b);
  mixm_k<<<NBLK, 256, 0, stream>>>(A, Bb, w3b, A, part);
  statsaffine_k<<<1, 64, 0, stream>>>(part, NBLK, 1.f / N2,
      (const float*)d_in[9], (const float*)d_in[10], 0, aA, bA);
  norm_res_k<<<N2 / 64, 256, 0, stream>>>(A, aA, bA, X, Xb, 0);

  // ---- conv weights
  wt_k<<<368640 / 256, 256, 0, stream>>>(res_w, wt);

  // ---- 5 residual layers x 2 convs
  const int dil[5] = {1, 2, 4, 2, 1};
  for (int layer = 0; layer < 5; ++layer){
    const int d = dil[layer];
    const int li0 = layer * 2, li1 = li0 + 1;
    launch_conv(d, Xb, wt + (size_t)li0 * 36864, A, part, stream);
    statsaffine_k<<<1, 64, 0, stream>>>(part, NBLK, 1.f / N2, res_g, res_be, li0 * CH, aA, bA);
    norm_nhwc_k<<<N2 * 64 / 4096, 256, 0, stream>>>(A, aA, bA);
    launch_conv(d, A, wt + (size_t)li1 * 36864, Bb, part, stream);
    statsaffine_k<<<1, 64, 0, stream>>>(part, NBLK, 1.f / N2, res_g, res_be, li1 * CH, aB, bB);
    norm_res_k<<<N2 / 64, 256, 0, stream>>>(Bb, aB, bB, X,
        (layer == 4) ? nullptr : Xb, 1);
  }
}